// Round 1
// baseline (174.656 us; speedup 1.0000x reference)
//
#include <hip/hip_runtime.h>
#include <math.h>

// z[i] = R @ x[i], R = ZYX-intrinsic Euler rotation from weight[3].
// x: [N,3] f32 row-major; out: [N,3] f32. N = 8,000,000 -> 24M floats = 6M float4
// = 2M groups of (3 float4 = 4 points).

__global__ __launch_bounds__(256) void rot_apply_kernel(
    const float* __restrict__ x,
    const float* __restrict__ w,
    float* __restrict__ out,
    long long n_groups)
{
    // --- compute R once per block, broadcast via LDS ---
    __shared__ float Rs[9];
    if (threadIdx.x == 0) {
        float a = w[0], b = w[1], c = w[2];
        float sa, ca, sb, cb, sc, cc;
        sincosf(a, &sa, &ca);
        sincosf(b, &sb, &cb);
        sincosf(c, &sc, &cc);
        Rs[0] = cc * cb;              // R00
        Rs[1] = sa * sb * cc - ca * sc; // R01
        Rs[2] = ca * sb * cc + sa * sc; // R02
        Rs[3] = cb * sc;              // R10
        Rs[4] = sa * sb * sc + ca * cc; // R11
        Rs[5] = ca * sb * sc - sa * cc; // R12
        Rs[6] = -sb;                  // R20
        Rs[7] = sa * cb;              // R21
        Rs[8] = ca * cb;              // R22
    }
    __syncthreads();
    const float R00 = Rs[0], R01 = Rs[1], R02 = Rs[2];
    const float R10 = Rs[3], R11 = Rs[4], R12 = Rs[5];
    const float R20 = Rs[6], R21 = Rs[7], R22 = Rs[8];

    const float4* __restrict__ x4 = (const float4*)x;
    float4* __restrict__ o4 = (float4*)out;

    const long long stride = (long long)gridDim.x * blockDim.x;
    for (long long g = (long long)blockIdx.x * blockDim.x + threadIdx.x;
         g < n_groups; g += stride) {
        const long long base = 3ll * g;
        float4 v0 = x4[base + 0];
        float4 v1 = x4[base + 1];
        float4 v2 = x4[base + 2];

        // 4 points packed in 3 float4s:
        // p0=(v0.x,v0.y,v0.z) p1=(v0.w,v1.x,v1.y) p2=(v1.z,v1.w,v2.x) p3=(v2.y,v2.z,v2.w)
        float px0 = v0.x, py0 = v0.y, pz0 = v0.z;
        float px1 = v0.w, py1 = v1.x, pz1 = v1.y;
        float px2 = v1.z, py2 = v1.w, pz2 = v2.x;
        float px3 = v2.y, py3 = v2.z, pz3 = v2.w;

        float a0 = fmaf(R00, px0, fmaf(R01, py0, R02 * pz0));
        float b0 = fmaf(R10, px0, fmaf(R11, py0, R12 * pz0));
        float c0 = fmaf(R20, px0, fmaf(R21, py0, R22 * pz0));

        float a1 = fmaf(R00, px1, fmaf(R01, py1, R02 * pz1));
        float b1 = fmaf(R10, px1, fmaf(R11, py1, R12 * pz1));
        float c1 = fmaf(R20, px1, fmaf(R21, py1, R22 * pz1));

        float a2 = fmaf(R00, px2, fmaf(R01, py2, R02 * pz2));
        float b2 = fmaf(R10, px2, fmaf(R11, py2, R12 * pz2));
        float c2 = fmaf(R20, px2, fmaf(R21, py2, R22 * pz2));

        float a3 = fmaf(R00, px3, fmaf(R01, py3, R02 * pz3));
        float b3 = fmaf(R10, px3, fmaf(R11, py3, R12 * pz3));
        float c3 = fmaf(R20, px3, fmaf(R21, py3, R22 * pz3));

        float4 w0, w1, w2;
        w0.x = a0; w0.y = b0; w0.z = c0; w0.w = a1;
        w1.x = b1; w1.y = c1; w1.z = a2; w1.w = b2;
        w2.x = c2; w2.y = a3; w2.z = b3; w2.w = c3;

        o4[base + 0] = w0;
        o4[base + 1] = w1;
        o4[base + 2] = w2;
    }
}

extern "C" void kernel_launch(void* const* d_in, const int* in_sizes, int n_in,
                              void* d_out, int out_size, void* d_ws, size_t ws_size,
                              hipStream_t stream) {
    const float* x = (const float*)d_in[0];
    const float* w = (const float*)d_in[1];
    float* out = (float*)d_out;

    const long long n_floats = (long long)in_sizes[0];   // 3*N = 24,000,000
    const long long n_groups = n_floats / 12;            // 2,000,000 (exact)

    const int block = 256;
    int grid = 2048;  // grid-stride; memory-bound cap per Guideline 11
    long long needed = (n_groups + block - 1) / block;
    if (needed < grid) grid = (int)needed;

    rot_apply_kernel<<<grid, block, 0, stream>>>(x, w, out, n_groups);
}

// Round 2
// 171.668 us; speedup vs baseline: 1.0174x; 1.0174x over previous
//
#include <hip/hip_runtime.h>
#include <math.h>

// z[i] = R @ x[i], R from ZYX-intrinsic Euler angles in weight[3].
// x/out: [N,3] f32 row-major. N = 8,000,000 -> 24M floats = 6M float4.
// LDS-staged tile so ALL global traffic is lane-contiguous float4
// (previous version had stride-48B lanes -> 3x request amplification -> 2.4 TB/s).

#define BLOCK 256
#define TILE_F4 (BLOCK * 3)   // 768 float4 = 12 KB = 1024 points per block

__global__ __launch_bounds__(BLOCK) void rot_apply_lds_kernel(
    const float* __restrict__ x,
    const float* __restrict__ w,
    float* __restrict__ out,
    long long n4)            // total float4 count (6,000,000)
{
    __shared__ float4 s_in[TILE_F4];
    __shared__ float4 s_out[TILE_F4];
    __shared__ float Rs[9];

    const int t = threadIdx.x;

    if (t == 0) {
        float a = w[0], b = w[1], c = w[2];
        float sa, ca, sb, cb, sc, cc;
        sincosf(a, &sa, &ca);
        sincosf(b, &sb, &cb);
        sincosf(c, &sc, &cc);
        Rs[0] = cc * cb;                // R00
        Rs[1] = sa * sb * cc - ca * sc; // R01
        Rs[2] = ca * sb * cc + sa * sc; // R02
        Rs[3] = cb * sc;                // R10
        Rs[4] = sa * sb * sc + ca * cc; // R11
        Rs[5] = ca * sb * sc - sa * cc; // R12
        Rs[6] = -sb;                    // R20
        Rs[7] = sa * cb;                // R21
        Rs[8] = ca * cb;                // R22
    }

    const float4* __restrict__ x4 = (const float4*)x;
    float4* __restrict__ o4 = (float4*)out;

    const long long tileBase = (long long)blockIdx.x * TILE_F4;

    // ---- phase 1: coalesced global -> LDS (lane-contiguous float4) ----
#pragma unroll
    for (int k = 0; k < 3; ++k) {
        long long gi = tileBase + (long long)k * BLOCK + t;
        if (gi < n4) s_in[k * BLOCK + t] = x4[gi];
    }
    __syncthreads();   // also publishes Rs

    const float R00 = Rs[0], R01 = Rs[1], R02 = Rs[2];
    const float R10 = Rs[3], R11 = Rs[4], R12 = Rs[5];
    const float R20 = Rs[6], R21 = Rs[7], R22 = Rs[8];

    // ---- phase 2: rotate 4 points (3 float4) per thread via LDS ----
    // stride-48B LDS reads: lanes t and t+8 alias banks -> 2-way, free (m136)
    float4 v0 = s_in[3 * t + 0];
    float4 v1 = s_in[3 * t + 1];
    float4 v2 = s_in[3 * t + 2];

    float px0 = v0.x, py0 = v0.y, pz0 = v0.z;
    float px1 = v0.w, py1 = v1.x, pz1 = v1.y;
    float px2 = v1.z, py2 = v1.w, pz2 = v2.x;
    float px3 = v2.y, py3 = v2.z, pz3 = v2.w;

    float a0 = fmaf(R00, px0, fmaf(R01, py0, R02 * pz0));
    float b0 = fmaf(R10, px0, fmaf(R11, py0, R12 * pz0));
    float c0 = fmaf(R20, px0, fmaf(R21, py0, R22 * pz0));

    float a1 = fmaf(R00, px1, fmaf(R01, py1, R02 * pz1));
    float b1 = fmaf(R10, px1, fmaf(R11, py1, R12 * pz1));
    float c1 = fmaf(R20, px1, fmaf(R21, py1, R22 * pz1));

    float a2 = fmaf(R00, px2, fmaf(R01, py2, R02 * pz2));
    float b2 = fmaf(R10, px2, fmaf(R11, py2, R12 * pz2));
    float c2 = fmaf(R20, px2, fmaf(R21, py2, R22 * pz2));

    float a3 = fmaf(R00, px3, fmaf(R01, py3, R02 * pz3));
    float b3 = fmaf(R10, px3, fmaf(R11, py3, R12 * pz3));
    float c3 = fmaf(R20, px3, fmaf(R21, py3, R22 * pz3));

    float4 w0, w1, w2;
    w0.x = a0; w0.y = b0; w0.z = c0; w0.w = a1;
    w1.x = b1; w1.y = c1; w1.z = a2; w1.w = b2;
    w2.x = c2; w2.y = a3; w2.z = b3; w2.w = c3;

    s_out[3 * t + 0] = w0;
    s_out[3 * t + 1] = w1;
    s_out[3 * t + 2] = w2;
    __syncthreads();

    // ---- phase 3: coalesced LDS -> global (lane-contiguous float4) ----
#pragma unroll
    for (int k = 0; k < 3; ++k) {
        long long gi = tileBase + (long long)k * BLOCK + t;
        if (gi < n4) o4[gi] = s_out[k * BLOCK + t];
    }
}

extern "C" void kernel_launch(void* const* d_in, const int* in_sizes, int n_in,
                              void* d_out, int out_size, void* d_ws, size_t ws_size,
                              hipStream_t stream) {
    const float* x = (const float*)d_in[0];
    const float* w = (const float*)d_in[1];
    float* out = (float*)d_out;

    const long long n_floats = (long long)in_sizes[0];   // 24,000,000
    const long long n4 = n_floats / 4;                   // 6,000,000

    const long long grid = (n4 + TILE_F4 - 1) / TILE_F4; // 7813

    rot_apply_lds_kernel<<<(int)grid, BLOCK, 0, stream>>>(x, w, out, n4);
}